// Round 2
// baseline (341.125 us; speedup 1.0000x reference)
//
#include <hip/hip_runtime.h>
#include <math.h>

#define N_NODES 50000
#define N_EDGES 800000
#define IN_F 128
#define OUT_F 64
#define LRELU_ALPHA 0.2f

__device__ inline float wred_max(float v) {
#pragma unroll
    for (int o = 32; o > 0; o >>= 1) v = fmaxf(v, __shfl_down(v, o, 64));
    return v;
}
__device__ inline float wred_sum(float v) {
#pragma unroll
    for (int o = 32; o > 0; o >>= 1) v += __shfl_down(v, o, 64);
    return v;
}

// K1: Wh = x @ W (4 rows/block, one wave per row), plus s[n]=Wh[n]·a_top, t[n]=Wh[n]·a_bot
__global__ __launch_bounds__(256) void k_wh(const float* __restrict__ x,
                                            const float* __restrict__ W,
                                            const float* __restrict__ a,
                                            float* __restrict__ Wh,
                                            float* __restrict__ sv,
                                            float* __restrict__ tv) {
    __shared__ float Ws[IN_F * OUT_F];   // 32 KB
    __shared__ float xs[4][IN_F];        // 2 KB
    __shared__ float atop[OUT_F], abot[OUT_F];

    for (int i = threadIdx.x; i < IN_F * OUT_F; i += 256) Ws[i] = W[i];
    if (threadIdx.x < OUT_F) {
        atop[threadIdx.x] = a[threadIdx.x];
        abot[threadIdx.x] = a[OUT_F + threadIdx.x];
    }
    int row0 = blockIdx.x * 4;
    for (int i = threadIdx.x; i < 4 * IN_F; i += 256) {
        int r = row0 + i / IN_F;
        xs[i / IN_F][i % IN_F] = (r < N_NODES) ? x[r * IN_F + (i % IN_F)] : 0.0f;
    }
    __syncthreads();

    int lr = threadIdx.x >> 6;
    int c  = threadIdx.x & 63;
    int r  = row0 + lr;
    float acc = 0.0f;
#pragma unroll 8
    for (int k = 0; k < IN_F; k++)
        acc = fmaf(xs[lr][k], Ws[k * OUT_F + c], acc);

    if (r < N_NODES) Wh[r * OUT_F + c] = acc;
    float ss = wred_sum(acc * atop[c]);
    float tt = wred_sum(acc * abot[c]);
    if (c == 0 && r < N_NODES) { sv[r] = ss; tv[r] = tt; }
}

// K2: e_j = leaky_relu(s[src_j] + t[dst_j]); per-block max -> pmax
__global__ __launch_bounds__(256) void k_edge(const int* __restrict__ src,
                                              const int* __restrict__ dst,
                                              const float* __restrict__ sv,
                                              const float* __restrict__ tv,
                                              float* __restrict__ e,
                                              float* __restrict__ pmax) {
    int base = blockIdx.x * 1024 + threadIdx.x;
    float lmax = -INFINITY;
#pragma unroll
    for (int i = 0; i < 4; i++) {
        int j = base + i * 256;
        if (j < N_EDGES) {
            float v = sv[src[j]] + tv[dst[j]];
            v = v > 0.0f ? v : LRELU_ALPHA * v;
            e[j] = v;
            lmax = fmaxf(lmax, v);
        }
    }
    __shared__ float red[4];
    float wm = wred_max(lmax);
    if ((threadIdx.x & 63) == 0) red[threadIdx.x >> 6] = wm;
    __syncthreads();
    if (threadIdx.x == 0)
        pmax[blockIdx.x] = fmaxf(fmaxf(red[0], red[1]), fmaxf(red[2], red[3]));
}

__global__ __launch_bounds__(1024) void k_rmax(const float* __restrict__ pmax, int n,
                                               float* __restrict__ gmax) {
    float lmax = -INFINITY;
    for (int i = threadIdx.x; i < n; i += 1024) lmax = fmaxf(lmax, pmax[i]);
    __shared__ float red[16];
    float wm = wred_max(lmax);
    if ((threadIdx.x & 63) == 0) red[threadIdx.x >> 6] = wm;
    __syncthreads();
    if (threadIdx.x == 0) {
        float m = -INFINITY;
        for (int i = 0; i < 16; i++) m = fmaxf(m, red[i]);
        gmax[0] = m;
    }
}

// K3b: e_j <- exp(e_j - gmax); per-block sum -> psum
__global__ __launch_bounds__(256) void k_exp(float* __restrict__ e,
                                             const float* __restrict__ gmax,
                                             float* __restrict__ psum) {
    float gm = gmax[0];
    int base = blockIdx.x * 1024 + threadIdx.x;
    float lsum = 0.0f;
#pragma unroll
    for (int i = 0; i < 4; i++) {
        int j = base + i * 256;
        if (j < N_EDGES) {
            float p = expf(e[j] - gm);
            e[j] = p;
            lsum += p;
        }
    }
    __shared__ float red[4];
    float wsm = wred_sum(lsum);
    if ((threadIdx.x & 63) == 0) red[threadIdx.x >> 6] = wsm;
    __syncthreads();
    if (threadIdx.x == 0)
        psum[blockIdx.x] = red[0] + red[1] + red[2] + red[3];
}

__global__ __launch_bounds__(1024) void k_rsum(const float* __restrict__ psum, int n,
                                               float* __restrict__ ginv) {
    float lsum = 0.0f;
    for (int i = threadIdx.x; i < n; i += 1024) lsum += psum[i];
    __shared__ float red[16];
    float wsm = wred_sum(lsum);
    if ((threadIdx.x & 63) == 0) red[threadIdx.x >> 6] = wsm;
    __syncthreads();
    if (threadIdx.x == 0) {
        float s = 0.0f;
        for (int i = 0; i < 16; i++) s += red[i];
        ginv[0] = 1.0f / s;
    }
}

// --- counting sort by src ---
__global__ void k_zero_i(int* __restrict__ p, int n) {
    int i = blockIdx.x * 256 + threadIdx.x;
    if (i < n) p[i] = 0;
}

__global__ void k_hist(const int* __restrict__ src, int* __restrict__ cnt) {
    int j = blockIdx.x * 256 + threadIdx.x;
    if (j < N_EDGES) atomicAdd(&cnt[src[j]], 1);
}

// exclusive prefix sum of cnt -> off (and head copy); off[N_NODES] = N_EDGES
__global__ __launch_bounds__(1024) void k_scan(const int* __restrict__ cnt,
                                               int* __restrict__ off,
                                               int* __restrict__ head) {
    __shared__ int sums[1024];
    const int CH = (N_NODES + 1023) / 1024;  // 49
    int t = threadIdx.x;
    int b0 = t * CH;
    int s = 0;
    for (int i = 0; i < CH; i++) {
        int idx = b0 + i;
        if (idx < N_NODES) s += cnt[idx];
    }
    sums[t] = s;
    __syncthreads();
    for (int o = 1; o < 1024; o <<= 1) {
        int v = (t >= o) ? sums[t - o] : 0;
        __syncthreads();
        sums[t] += v;
        __syncthreads();
    }
    int run = (t == 0) ? 0 : sums[t - 1];
    for (int i = 0; i < CH; i++) {
        int idx = b0 + i;
        if (idx < N_NODES) {
            off[idx] = run;
            head[idx] = run;
            run += cnt[idx];
        }
    }
    if (t == 0) off[N_NODES] = N_EDGES;
}

__global__ void k_perm(const int* __restrict__ src, int* __restrict__ head,
                       int* __restrict__ perm) {
    int j = blockIdx.x * 256 + threadIdx.x;
    if (j < N_EDGES) {
        int p = atomicAdd(&head[src[j]], 1);
        perm[p] = j;
    }
}

// K4: per-node gather: out[n] = elu( ginv * sum_{j in edges(n)} e_j * Wh[dst_j] )
// one wave per node, lane = feature
__global__ __launch_bounds__(256) void k_gather(const int* __restrict__ off,
                                                const int* __restrict__ perm,
                                                const int* __restrict__ dst,
                                                const float* __restrict__ e,
                                                const float* __restrict__ ginv,
                                                const float* __restrict__ Wh,
                                                float* __restrict__ out) {
    int n = blockIdx.x * 4 + (threadIdx.x >> 6);
    int f = threadIdx.x & 63;
    if (n >= N_NODES) return;
    int start = off[n], end = off[n + 1];
    float acc = 0.0f;
    for (int base = start; base < end; base += 64) {
        int cnt = end - base;
        if (cnt > 64) cnt = 64;
        int dj = 0;
        float att = 0.0f;
        if (f < cnt) {
            int j = perm[base + f];
            att = e[j];
            dj = dst[j];
        }
        int i = 0;
        for (; i + 3 < cnt; i += 4) {
            int j0 = __shfl(dj, i, 64), j1 = __shfl(dj, i + 1, 64);
            int j2 = __shfl(dj, i + 2, 64), j3 = __shfl(dj, i + 3, 64);
            float a0 = __shfl(att, i, 64), a1 = __shfl(att, i + 1, 64);
            float a2 = __shfl(att, i + 2, 64), a3 = __shfl(att, i + 3, 64);
            float w0 = Wh[(size_t)j0 * OUT_F + f];
            float w1 = Wh[(size_t)j1 * OUT_F + f];
            float w2 = Wh[(size_t)j2 * OUT_F + f];
            float w3 = Wh[(size_t)j3 * OUT_F + f];
            acc = fmaf(a0, w0, acc);
            acc = fmaf(a1, w1, acc);
            acc = fmaf(a2, w2, acc);
            acc = fmaf(a3, w3, acc);
        }
        for (; i < cnt; i++) {
            int jj = __shfl(dj, i, 64);
            float aa = __shfl(att, i, 64);
            acc = fmaf(aa, Wh[(size_t)jj * OUT_F + f], acc);
        }
    }
    acc *= ginv[0];
    out[(size_t)n * OUT_F + f] = acc > 0.0f ? acc : expm1f(acc);
}

extern "C" void kernel_launch(void* const* d_in, const int* in_sizes, int n_in,
                              void* d_out, int out_size, void* d_ws, size_t ws_size,
                              hipStream_t stream) {
    const float* x  = (const float*)d_in[0];
    const int*   ei = (const int*)d_in[1];
    const float* W  = (const float*)d_in[2];
    const float* a  = (const float*)d_in[3];
    float* out = (float*)d_out;

    const int* src = ei;            // edge_index[0]
    const int* dst = ei + N_EDGES;  // edge_index[1]

    float* ws   = (float*)d_ws;
    float* Wh   = ws;                                  // 3,200,000 f
    float* sv   = Wh + (size_t)N_NODES * OUT_F;        // 50,000 f
    float* tv   = sv + N_NODES;                        // 50,000 f
    float* e    = tv + N_NODES;                        // 800,000 f
    float* pmax = e + N_EDGES;                         // 1,024 f
    float* psum = pmax + 1024;                         // 1,024 f
    float* gmax = psum + 1024;                         // 1 f
    float* ginv = gmax + 1;                            // 1 f
    int*   cnt  = (int*)(ginv + 1);                    // 50,000 i
    int*   off  = cnt + N_NODES;                       // 50,001 i
    int*   head = off + N_NODES + 1;                   // 50,000 i
    int*   perm = head + N_NODES;                      // 800,000 i

    const int NB2 = (N_EDGES + 1023) / 1024;  // 782
    const int NBE = (N_EDGES + 255) / 256;    // 3125

    k_zero_i<<<(N_NODES + 255) / 256, 256, 0, stream>>>(cnt, N_NODES);
    k_wh<<<(N_NODES + 3) / 4, 256, 0, stream>>>(x, W, a, Wh, sv, tv);
    k_hist<<<NBE, 256, 0, stream>>>(src, cnt);
    k_scan<<<1, 1024, 0, stream>>>(cnt, off, head);
    k_perm<<<NBE, 256, 0, stream>>>(src, head, perm);
    k_edge<<<NB2, 256, 0, stream>>>(src, dst, sv, tv, e, pmax);
    k_rmax<<<1, 1024, 0, stream>>>(pmax, NB2, gmax);
    k_exp<<<NB2, 256, 0, stream>>>(e, gmax, psum);
    k_rsum<<<1, 1024, 0, stream>>>(psum, NB2, ginv);
    k_gather<<<(N_NODES + 3) / 4, 256, 0, stream>>>(off, perm, dst, e, ginv, Wh, out);
}

// Round 3
// 194.899 us; speedup vs baseline: 1.7503x; 1.7503x over previous
//
#include <hip/hip_runtime.h>
#include <math.h>

#define N_NODES 50000
#define N_EDGES 800000
#define IN_F 128
#define OUT_F 64
#define LRELU_ALPHA 0.2f

__device__ inline float wred_max(float v) {
#pragma unroll
    for (int o = 32; o > 0; o >>= 1) v = fmaxf(v, __shfl_down(v, o, 64));
    return v;
}
__device__ inline float wred_sum(float v) {
#pragma unroll
    for (int o = 32; o > 0; o >>= 1) v += __shfl_down(v, o, 64);
    return v;
}

// K1: Wh = x @ W (4 rows/block, one wave per row), plus s[n]=Wh[n]·a_top, t[n]=Wh[n]·a_bot
__global__ __launch_bounds__(256) void k_wh(const float* __restrict__ x,
                                            const float* __restrict__ W,
                                            const float* __restrict__ a,
                                            float* __restrict__ Wh,
                                            float* __restrict__ sv,
                                            float* __restrict__ tv) {
    __shared__ float Ws[IN_F * OUT_F];   // 32 KB
    __shared__ float xs[4][IN_F];        // 2 KB
    __shared__ float atop[OUT_F], abot[OUT_F];

    for (int i = threadIdx.x; i < IN_F * OUT_F; i += 256) Ws[i] = W[i];
    if (threadIdx.x < OUT_F) {
        atop[threadIdx.x] = a[threadIdx.x];
        abot[threadIdx.x] = a[OUT_F + threadIdx.x];
    }
    int row0 = blockIdx.x * 4;
    for (int i = threadIdx.x; i < 4 * IN_F; i += 256) {
        int r = row0 + i / IN_F;
        xs[i / IN_F][i % IN_F] = (r < N_NODES) ? x[r * IN_F + (i % IN_F)] : 0.0f;
    }
    __syncthreads();

    int lr = threadIdx.x >> 6;
    int c  = threadIdx.x & 63;
    int r  = row0 + lr;
    float acc = 0.0f;
#pragma unroll 8
    for (int k = 0; k < IN_F; k++)
        acc = fmaf(xs[lr][k], Ws[k * OUT_F + c], acc);

    if (r < N_NODES) Wh[r * OUT_F + c] = acc;
    float ss = wred_sum(acc * atop[c]);
    float tt = wred_sum(acc * abot[c]);
    if (c == 0 && r < N_NODES) { sv[r] = ss; tv[r] = tt; }
}

// --- counting sort by src: histogram ---
__global__ void k_zero_i(int* __restrict__ p, int n) {
    int i = blockIdx.x * 256 + threadIdx.x;
    if (i < n) p[i] = 0;
}

__global__ void k_hist(const int* __restrict__ src, int* __restrict__ cnt) {
    int j = blockIdx.x * 256 + threadIdx.x;
    if (j < N_EDGES) atomicAdd(&cnt[src[j]], 1);
}

// hierarchical exclusive scan: per-block scan + block totals
__global__ __launch_bounds__(256) void k_scan1(const int* __restrict__ cnt,
                                               int* __restrict__ off,
                                               int* __restrict__ bsum) {
    __shared__ int s[256];
    int t = threadIdx.x;
    int i = blockIdx.x * 256 + t;
    int c = (i < N_NODES) ? cnt[i] : 0;
    s[t] = c;
    __syncthreads();
#pragma unroll
    for (int o = 1; o < 256; o <<= 1) {
        int v = (t >= o) ? s[t - o] : 0;
        __syncthreads();
        s[t] += v;
        __syncthreads();
    }
    if (i < N_NODES) off[i] = s[t] - c;       // block-local exclusive
    if (t == 255) bsum[blockIdx.x] = s[255];  // block total
}

__global__ __launch_bounds__(256) void k_scan2(const int* __restrict__ bsum, int nb,
                                               int* __restrict__ boff) {
    __shared__ int s[256];
    int t = threadIdx.x;
    int c = (t < nb) ? bsum[t] : 0;
    s[t] = c;
    __syncthreads();
#pragma unroll
    for (int o = 1; o < 256; o <<= 1) {
        int v = (t >= o) ? s[t - o] : 0;
        __syncthreads();
        s[t] += v;
        __syncthreads();
    }
    if (t < nb) boff[t] = s[t] - c;
}

__global__ __launch_bounds__(256) void k_scan3(int* __restrict__ off,
                                               int* __restrict__ head,
                                               const int* __restrict__ boff) {
    int i = blockIdx.x * 256 + threadIdx.x;
    if (i < N_NODES) {
        int v = off[i] + boff[blockIdx.x];
        off[i] = v;
        head[i] = v;
    }
    if (i == 0) off[N_NODES] = N_EDGES;
}

// fused permutation + edge score: writes esorted/dsorted in src-sorted order
__global__ __launch_bounds__(256) void k_permedge(const int* __restrict__ src,
                                                  const int* __restrict__ dst,
                                                  const float* __restrict__ sv,
                                                  const float* __restrict__ tv,
                                                  int* __restrict__ head,
                                                  float* __restrict__ esorted,
                                                  int* __restrict__ dsorted,
                                                  float* __restrict__ pmax) {
    int j = blockIdx.x * 256 + threadIdx.x;
    float v = -INFINITY;
    if (j < N_EDGES) {
        int s = src[j], d = dst[j];
        int p = atomicAdd(&head[s], 1);
        v = sv[s] + tv[d];
        v = v > 0.0f ? v : LRELU_ALPHA * v;
        esorted[p] = v;
        dsorted[p] = d;
    }
    __shared__ float red[4];
    float wm = wred_max(v);
    if ((threadIdx.x & 63) == 0) red[threadIdx.x >> 6] = wm;
    __syncthreads();
    if (threadIdx.x == 0)
        pmax[blockIdx.x] = fmaxf(fmaxf(red[0], red[1]), fmaxf(red[2], red[3]));
}

__global__ __launch_bounds__(1024) void k_rmax(const float* __restrict__ pmax, int n,
                                               float* __restrict__ gmax) {
    float lmax = -INFINITY;
    for (int i = threadIdx.x; i < n; i += 1024) lmax = fmaxf(lmax, pmax[i]);
    __shared__ float red[16];
    float wm = wred_max(lmax);
    if ((threadIdx.x & 63) == 0) red[threadIdx.x >> 6] = wm;
    __syncthreads();
    if (threadIdx.x == 0) {
        float m = -INFINITY;
        for (int i = 0; i < 16; i++) m = fmaxf(m, red[i]);
        gmax[0] = m;
    }
}

// esorted <- exp(esorted - gmax), coalesced; per-block sum
__global__ __launch_bounds__(256) void k_exp(float* __restrict__ e,
                                             const float* __restrict__ gmax,
                                             float* __restrict__ psum) {
    float gm = gmax[0];
    int base = blockIdx.x * 1024 + threadIdx.x;
    float lsum = 0.0f;
#pragma unroll
    for (int i = 0; i < 4; i++) {
        int j = base + i * 256;
        if (j < N_EDGES) {
            float p = expf(e[j] - gm);
            e[j] = p;
            lsum += p;
        }
    }
    __shared__ float red[4];
    float wsm = wred_sum(lsum);
    if ((threadIdx.x & 63) == 0) red[threadIdx.x >> 6] = wsm;
    __syncthreads();
    if (threadIdx.x == 0)
        psum[blockIdx.x] = red[0] + red[1] + red[2] + red[3];
}

__global__ __launch_bounds__(1024) void k_rsum(const float* __restrict__ psum, int n,
                                               float* __restrict__ ginv) {
    float lsum = 0.0f;
    for (int i = threadIdx.x; i < n; i += 1024) lsum += psum[i];
    __shared__ float red[16];
    float wsm = wred_sum(lsum);
    if ((threadIdx.x & 63) == 0) red[threadIdx.x >> 6] = wsm;
    __syncthreads();
    if (threadIdx.x == 0) {
        float s = 0.0f;
        for (int i = 0; i < 16; i++) s += red[i];
        ginv[0] = 1.0f / s;
    }
}

// K4: per-node gather: out[n] = elu( ginv * sum_{k in [off[n],off[n+1])} es_k * Wh[ds_k] )
// one wave per node, lane = feature; es/ds reads coalesced
__global__ __launch_bounds__(256) void k_gather(const int* __restrict__ off,
                                                const float* __restrict__ es,
                                                const int* __restrict__ ds,
                                                const float* __restrict__ ginv,
                                                const float* __restrict__ Wh,
                                                float* __restrict__ out) {
    int n = blockIdx.x * 4 + (threadIdx.x >> 6);
    int f = threadIdx.x & 63;
    if (n >= N_NODES) return;
    int start = off[n], end = off[n + 1];
    float acc = 0.0f;
    for (int base = start; base < end; base += 64) {
        int cnt = end - base;
        if (cnt > 64) cnt = 64;
        int dj = 0;
        float att = 0.0f;
        if (f < cnt) {
            att = es[base + f];
            dj = ds[base + f];
        }
        int i = 0;
        for (; i + 3 < cnt; i += 4) {
            int j0 = __shfl(dj, i, 64), j1 = __shfl(dj, i + 1, 64);
            int j2 = __shfl(dj, i + 2, 64), j3 = __shfl(dj, i + 3, 64);
            float a0 = __shfl(att, i, 64), a1 = __shfl(att, i + 1, 64);
            float a2 = __shfl(att, i + 2, 64), a3 = __shfl(att, i + 3, 64);
            float w0 = Wh[(size_t)j0 * OUT_F + f];
            float w1 = Wh[(size_t)j1 * OUT_F + f];
            float w2 = Wh[(size_t)j2 * OUT_F + f];
            float w3 = Wh[(size_t)j3 * OUT_F + f];
            acc = fmaf(a0, w0, acc);
            acc = fmaf(a1, w1, acc);
            acc = fmaf(a2, w2, acc);
            acc = fmaf(a3, w3, acc);
        }
        for (; i < cnt; i++) {
            int jj = __shfl(dj, i, 64);
            float aa = __shfl(att, i, 64);
            acc = fmaf(aa, Wh[(size_t)jj * OUT_F + f], acc);
        }
    }
    acc *= ginv[0];
    out[(size_t)n * OUT_F + f] = acc > 0.0f ? acc : expm1f(acc);
}

extern "C" void kernel_launch(void* const* d_in, const int* in_sizes, int n_in,
                              void* d_out, int out_size, void* d_ws, size_t ws_size,
                              hipStream_t stream) {
    const float* x  = (const float*)d_in[0];
    const int*   ei = (const int*)d_in[1];
    const float* W  = (const float*)d_in[2];
    const float* a  = (const float*)d_in[3];
    float* out = (float*)d_out;

    const int* src = ei;            // edge_index[0]
    const int* dst = ei + N_EDGES;  // edge_index[1]

    float* ws      = (float*)d_ws;
    float* Wh      = ws;                               // 3,200,000 f
    float* sv      = Wh + (size_t)N_NODES * OUT_F;     // 50,000 f
    float* tv      = sv + N_NODES;                     // 50,000 f
    float* esorted = tv + N_NODES;                     // 800,000 f
    float* pmax    = esorted + N_EDGES;                // 4,096 f
    float* psum    = pmax + 4096;                      // 1,024 f
    float* gmax    = psum + 1024;                      // 1 f
    float* ginv    = gmax + 1;                         // 1 f
    int*   cnt     = (int*)(ginv + 1);                 // 50,000 i
    int*   off     = cnt + N_NODES;                    // 50,001 i
    int*   head    = off + N_NODES + 1;                // 50,000 i
    int*   dsorted = head + N_NODES;                   // 800,000 i
    int*   bsum    = dsorted + N_EDGES;                // 256 i
    int*   boff    = bsum + 256;                       // 256 i

    const int NBN = (N_NODES + 255) / 256;   // 196
    const int NBE = (N_EDGES + 255) / 256;   // 3125
    const int NB2 = (N_EDGES + 1023) / 1024; // 782

    k_zero_i<<<NBN, 256, 0, stream>>>(cnt, N_NODES);
    k_wh<<<(N_NODES + 3) / 4, 256, 0, stream>>>(x, W, a, Wh, sv, tv);
    k_hist<<<NBE, 256, 0, stream>>>(src, cnt);
    k_scan1<<<NBN, 256, 0, stream>>>(cnt, off, bsum);
    k_scan2<<<1, 256, 0, stream>>>(bsum, NBN, boff);
    k_scan3<<<NBN, 256, 0, stream>>>(off, head, boff);
    k_permedge<<<NBE, 256, 0, stream>>>(src, dst, sv, tv, head, esorted, dsorted, pmax);
    k_rmax<<<1, 1024, 0, stream>>>(pmax, NBE, gmax);
    k_exp<<<NB2, 256, 0, stream>>>(esorted, gmax, psum);
    k_rsum<<<1, 1024, 0, stream>>>(psum, NB2, ginv);
    k_gather<<<(N_NODES + 3) / 4, 256, 0, stream>>>(off, esorted, dsorted, ginv, Wh, out);
}

// Round 4
// 170.653 us; speedup vs baseline: 1.9989x; 1.1421x over previous
//
#include <hip/hip_runtime.h>
#include <math.h>

#define N_NODES 50000
#define N_EDGES 800000
#define IN_F 128
#define OUT_F 64
#define LRELU_ALPHA 0.2f

__device__ inline float wred_max(float v) {
#pragma unroll
    for (int o = 32; o > 0; o >>= 1) v = fmaxf(v, __shfl_down(v, o, 64));
    return v;
}
__device__ inline float wred_sum(float v) {
#pragma unroll
    for (int o = 32; o > 0; o >>= 1) v += __shfl_down(v, o, 64);
    return v;
}

// K1: Wh = x @ W, register-tiled: 64x64 tile per block, 4x4 per thread.
// Also s[n]=Wh[n]·a_top, t[n]=Wh[n]·a_bot via in-wave reduction over tx.
__global__ __launch_bounds__(256, 2) void k_wh(const float* __restrict__ x,
                                               const float* __restrict__ W,
                                               const float* __restrict__ a,
                                               float* __restrict__ Wh,
                                               float* __restrict__ sv,
                                               float* __restrict__ tv) {
    __shared__ float xs[64 * 128];  // x tile, XOR-swizzled: addr = r*128 + (k ^ ((r&7)<<2))
    __shared__ float Ws[128 * 64];  // W, natural layout

    const int tid = threadIdx.x;
    const int row0 = blockIdx.x * 64;

    // stage x tile: coalesced float4 global reads, swizzled LDS writes (conflict-free)
    for (int i = tid; i < 64 * 32; i += 256) {
        int rl = i >> 5, c4 = (i & 31) << 2;
        int r = row0 + rl;
        float4 v = make_float4(0.f, 0.f, 0.f, 0.f);
        if (r < N_NODES) v = *reinterpret_cast<const float4*>(x + (size_t)r * IN_F + c4);
        int sw = c4 ^ ((rl & 7) << 2);
        *reinterpret_cast<float4*>(&xs[rl * 128 + sw]) = v;
    }
    // stage W: straight float4 copy
    for (int i = tid; i < 128 * 16; i += 256) {
        int k = i >> 4, c4 = (i & 15) << 2;
        *reinterpret_cast<float4*>(&Ws[k * 64 + c4]) =
            *reinterpret_cast<const float4*>(W + k * 64 + c4);
    }
    __syncthreads();

    const int tx = tid & 15;   // col group (4 cols)
    const int ty = tid >> 4;   // row group (4 rows)
    const int c0 = tx << 2;
    const int rl0 = ty << 2;

    float acc[4][4] = {};
#pragma unroll 4
    for (int k = 0; k < 128; ++k) {
        float4 b = *reinterpret_cast<const float4*>(&Ws[k * 64 + c0]);
        float a0 = xs[(rl0 + 0) * 128 + (k ^ (((rl0 + 0) & 7) << 2))];
        float a1 = xs[(rl0 + 1) * 128 + (k ^ (((rl0 + 1) & 7) << 2))];
        float a2 = xs[(rl0 + 2) * 128 + (k ^ (((rl0 + 2) & 7) << 2))];
        float a3 = xs[(rl0 + 3) * 128 + (k ^ (((rl0 + 3) & 7) << 2))];
        acc[0][0] = fmaf(a0, b.x, acc[0][0]);
        acc[0][1] = fmaf(a0, b.y, acc[0][1]);
        acc[0][2] = fmaf(a0, b.z, acc[0][2]);
        acc[0][3] = fmaf(a0, b.w, acc[0][3]);
        acc[1][0] = fmaf(a1, b.x, acc[1][0]);
        acc[1][1] = fmaf(a1, b.y, acc[1][1]);
        acc[1][2] = fmaf(a1, b.z, acc[1][2]);
        acc[1][3] = fmaf(a1, b.w, acc[1][3]);
        acc[2][0] = fmaf(a2, b.x, acc[2][0]);
        acc[2][1] = fmaf(a2, b.y, acc[2][1]);
        acc[2][2] = fmaf(a2, b.z, acc[2][2]);
        acc[2][3] = fmaf(a2, b.w, acc[2][3]);
        acc[3][0] = fmaf(a3, b.x, acc[3][0]);
        acc[3][1] = fmaf(a3, b.y, acc[3][1]);
        acc[3][2] = fmaf(a3, b.z, acc[3][2]);
        acc[3][3] = fmaf(a3, b.w, acc[3][3]);
    }

    float at[4], ab[4];
#pragma unroll
    for (int i = 0; i < 4; i++) {
        at[i] = a[c0 + i];
        ab[i] = a[OUT_F + c0 + i];
    }

#pragma unroll
    for (int ri = 0; ri < 4; ++ri) {
        int r = row0 + rl0 + ri;
        float ps = 0.0f, pt = 0.0f;
#pragma unroll
        for (int ci = 0; ci < 4; ++ci) {
            ps = fmaf(acc[ri][ci], at[ci], ps);
            pt = fmaf(acc[ri][ci], ab[ci], pt);
        }
#pragma unroll
        for (int o = 1; o < 16; o <<= 1) {
            ps += __shfl_xor(ps, o, 64);
            pt += __shfl_xor(pt, o, 64);
        }
        if (r < N_NODES) {
            *reinterpret_cast<float4*>(Wh + (size_t)r * OUT_F + c0) =
                make_float4(acc[ri][0], acc[ri][1], acc[ri][2], acc[ri][3]);
            if (tx == 0) { sv[r] = ps; tv[r] = pt; }
        }
    }
}

// --- counting sort by src: histogram ---
__global__ void k_zero_i(int* __restrict__ p, int n) {
    int i = blockIdx.x * 256 + threadIdx.x;
    if (i < n) p[i] = 0;
}

__global__ void k_hist(const int* __restrict__ src, int* __restrict__ cnt) {
    int j = blockIdx.x * 256 + threadIdx.x;
    if (j < N_EDGES) atomicAdd(&cnt[src[j]], 1);
}

// hierarchical exclusive scan
__global__ __launch_bounds__(256) void k_scan1(const int* __restrict__ cnt,
                                               int* __restrict__ off,
                                               int* __restrict__ bsum) {
    __shared__ int s[256];
    int t = threadIdx.x;
    int i = blockIdx.x * 256 + t;
    int c = (i < N_NODES) ? cnt[i] : 0;
    s[t] = c;
    __syncthreads();
#pragma unroll
    for (int o = 1; o < 256; o <<= 1) {
        int v = (t >= o) ? s[t - o] : 0;
        __syncthreads();
        s[t] += v;
        __syncthreads();
    }
    if (i < N_NODES) off[i] = s[t] - c;
    if (t == 255) bsum[blockIdx.x] = s[255];
}

__global__ __launch_bounds__(256) void k_scan2(const int* __restrict__ bsum, int nb,
                                               int* __restrict__ boff) {
    __shared__ int s[256];
    int t = threadIdx.x;
    int c = (t < nb) ? bsum[t] : 0;
    s[t] = c;
    __syncthreads();
#pragma unroll
    for (int o = 1; o < 256; o <<= 1) {
        int v = (t >= o) ? s[t - o] : 0;
        __syncthreads();
        s[t] += v;
        __syncthreads();
    }
    if (t < nb) boff[t] = s[t] - c;
}

__global__ __launch_bounds__(256) void k_scan3(int* __restrict__ off,
                                               int* __restrict__ head,
                                               const int* __restrict__ boff) {
    int i = blockIdx.x * 256 + threadIdx.x;
    if (i < N_NODES) {
        int v = off[i] + boff[blockIdx.x];
        off[i] = v;
        head[i] = v;
    }
    if (i == 0) off[N_NODES] = N_EDGES;
}

// fused permutation + edge score
__global__ __launch_bounds__(256) void k_permedge(const int* __restrict__ src,
                                                  const int* __restrict__ dst,
                                                  const float* __restrict__ sv,
                                                  const float* __restrict__ tv,
                                                  int* __restrict__ head,
                                                  float* __restrict__ esorted,
                                                  int* __restrict__ dsorted,
                                                  float* __restrict__ pmax) {
    int j = blockIdx.x * 256 + threadIdx.x;
    float v = -INFINITY;
    if (j < N_EDGES) {
        int s = src[j], d = dst[j];
        int p = atomicAdd(&head[s], 1);
        v = sv[s] + tv[d];
        v = v > 0.0f ? v : LRELU_ALPHA * v;
        esorted[p] = v;
        dsorted[p] = d;
    }
    __shared__ float red[4];
    float wm = wred_max(v);
    if ((threadIdx.x & 63) == 0) red[threadIdx.x >> 6] = wm;
    __syncthreads();
    if (threadIdx.x == 0)
        pmax[blockIdx.x] = fmaxf(fmaxf(red[0], red[1]), fmaxf(red[2], red[3]));
}

__global__ __launch_bounds__(1024) void k_rmax(const float* __restrict__ pmax, int n,
                                               float* __restrict__ gmax) {
    float lmax = -INFINITY;
    for (int i = threadIdx.x; i < n; i += 1024) lmax = fmaxf(lmax, pmax[i]);
    __shared__ float red[16];
    float wm = wred_max(lmax);
    if ((threadIdx.x & 63) == 0) red[threadIdx.x >> 6] = wm;
    __syncthreads();
    if (threadIdx.x == 0) {
        float m = -INFINITY;
        for (int i = 0; i < 16; i++) m = fmaxf(m, red[i]);
        gmax[0] = m;
    }
}

__global__ __launch_bounds__(256) void k_exp(float* __restrict__ e,
                                             const float* __restrict__ gmax,
                                             float* __restrict__ psum) {
    float gm = gmax[0];
    int base = blockIdx.x * 1024 + threadIdx.x;
    float lsum = 0.0f;
#pragma unroll
    for (int i = 0; i < 4; i++) {
        int j = base + i * 256;
        if (j < N_EDGES) {
            float p = expf(e[j] - gm);
            e[j] = p;
            lsum += p;
        }
    }
    __shared__ float red[4];
    float wsm = wred_sum(lsum);
    if ((threadIdx.x & 63) == 0) red[threadIdx.x >> 6] = wsm;
    __syncthreads();
    if (threadIdx.x == 0)
        psum[blockIdx.x] = red[0] + red[1] + red[2] + red[3];
}

__global__ __launch_bounds__(1024) void k_rsum(const float* __restrict__ psum, int n,
                                               float* __restrict__ ginv) {
    float lsum = 0.0f;
    for (int i = threadIdx.x; i < n; i += 1024) lsum += psum[i];
    __shared__ float red[16];
    float wsm = wred_sum(lsum);
    if ((threadIdx.x & 63) == 0) red[threadIdx.x >> 6] = wsm;
    __syncthreads();
    if (threadIdx.x == 0) {
        float s = 0.0f;
        for (int i = 0; i < 16; i++) s += red[i];
        ginv[0] = 1.0f / s;
    }
}

// K4: per-node gather
__global__ __launch_bounds__(256) void k_gather(const int* __restrict__ off,
                                                const float* __restrict__ es,
                                                const int* __restrict__ ds,
                                                const float* __restrict__ ginv,
                                                const float* __restrict__ Wh,
                                                float* __restrict__ out) {
    int n = blockIdx.x * 4 + (threadIdx.x >> 6);
    int f = threadIdx.x & 63;
    if (n >= N_NODES) return;
    int start = off[n], end = off[n + 1];
    float acc = 0.0f;
    for (int base = start; base < end; base += 64) {
        int cnt = end - base;
        if (cnt > 64) cnt = 64;
        int dj = 0;
        float att = 0.0f;
        if (f < cnt) {
            att = es[base + f];
            dj = ds[base + f];
        }
        int i = 0;
        for (; i + 3 < cnt; i += 4) {
            int j0 = __shfl(dj, i, 64), j1 = __shfl(dj, i + 1, 64);
            int j2 = __shfl(dj, i + 2, 64), j3 = __shfl(dj, i + 3, 64);
            float a0 = __shfl(att, i, 64), a1 = __shfl(att, i + 1, 64);
            float a2 = __shfl(att, i + 2, 64), a3 = __shfl(att, i + 3, 64);
            float w0 = Wh[(size_t)j0 * OUT_F + f];
            float w1 = Wh[(size_t)j1 * OUT_F + f];
            float w2 = Wh[(size_t)j2 * OUT_F + f];
            float w3 = Wh[(size_t)j3 * OUT_F + f];
            acc = fmaf(a0, w0, acc);
            acc = fmaf(a1, w1, acc);
            acc = fmaf(a2, w2, acc);
            acc = fmaf(a3, w3, acc);
        }
        for (; i < cnt; i++) {
            int jj = __shfl(dj, i, 64);
            float aa = __shfl(att, i, 64);
            acc = fmaf(aa, Wh[(size_t)jj * OUT_F + f], acc);
        }
    }
    acc *= ginv[0];
    out[(size_t)n * OUT_F + f] = acc > 0.0f ? acc : expm1f(acc);
}

extern "C" void kernel_launch(void* const* d_in, const int* in_sizes, int n_in,
                              void* d_out, int out_size, void* d_ws, size_t ws_size,
                              hipStream_t stream) {
    const float* x  = (const float*)d_in[0];
    const int*   ei = (const int*)d_in[1];
    const float* W  = (const float*)d_in[2];
    const float* a  = (const float*)d_in[3];
    float* out = (float*)d_out;

    const int* src = ei;            // edge_index[0]
    const int* dst = ei + N_EDGES;  // edge_index[1]

    float* ws      = (float*)d_ws;
    float* Wh      = ws;                               // 3,200,000 f
    float* sv      = Wh + (size_t)N_NODES * OUT_F;     // 50,000 f
    float* tv      = sv + N_NODES;                     // 50,000 f
    float* esorted = tv + N_NODES;                     // 800,000 f
    float* pmax    = esorted + N_EDGES;                // 4,096 f
    float* psum    = pmax + 4096;                      // 1,024 f
    float* gmax    = psum + 1024;                      // 1 f
    float* ginv    = gmax + 1;                         // 1 f
    int*   cnt     = (int*)(ginv + 1);                 // 50,000 i
    int*   off     = cnt + N_NODES;                    // 50,001 i
    int*   head    = off + N_NODES + 1;                // 50,000 i
    int*   dsorted = head + N_NODES;                   // 800,000 i
    int*   bsum    = dsorted + N_EDGES;                // 256 i
    int*   boff    = bsum + 256;                       // 256 i

    const int NBN = (N_NODES + 255) / 256;   // 196
    const int NBE = (N_EDGES + 255) / 256;   // 3125
    const int NB2 = (N_EDGES + 1023) / 1024; // 782

    k_zero_i<<<NBN, 256, 0, stream>>>(cnt, N_NODES);
    k_wh<<<(N_NODES + 63) / 64, 256, 0, stream>>>(x, W, a, Wh, sv, tv);
    k_hist<<<NBE, 256, 0, stream>>>(src, cnt);
    k_scan1<<<NBN, 256, 0, stream>>>(cnt, off, bsum);
    k_scan2<<<1, 256, 0, stream>>>(bsum, NBN, boff);
    k_scan3<<<NBN, 256, 0, stream>>>(off, head, boff);
    k_permedge<<<NBE, 256, 0, stream>>>(src, dst, sv, tv, head, esorted, dsorted, pmax);
    k_rmax<<<1, 1024, 0, stream>>>(pmax, NBE, gmax);
    k_exp<<<NB2, 256, 0, stream>>>(esorted, gmax, psum);
    k_rsum<<<1, 1024, 0, stream>>>(psum, NB2, ginv);
    k_gather<<<(N_NODES + 3) / 4, 256, 0, stream>>>(off, esorted, dsorted, ginv, Wh, out);
}

// Round 5
// 161.638 us; speedup vs baseline: 2.1104x; 1.0558x over previous
//
#include <hip/hip_runtime.h>
#include <math.h>

#define N_NODES 50000
#define N_EDGES 800000
#define IN_F 128
#define OUT_F 64
#define LRELU_ALPHA 0.2f

__device__ inline float wred_max(float v) {
#pragma unroll
    for (int o = 32; o > 0; o >>= 1) v = fmaxf(v, __shfl_down(v, o, 64));
    return v;
}
__device__ inline float wred_sum(float v) {
#pragma unroll
    for (int o = 32; o > 0; o >>= 1) v += __shfl_down(v, o, 64);
    return v;
}

// K1: Wh = x @ W, register-tiled: 64x64 tile per block, 4x4 per thread.
__global__ __launch_bounds__(256, 2) void k_wh(const float* __restrict__ x,
                                               const float* __restrict__ W,
                                               const float* __restrict__ a,
                                               float* __restrict__ Wh,
                                               float* __restrict__ sv,
                                               float* __restrict__ tv) {
    __shared__ float xs[64 * 128];  // x tile, XOR-swizzled
    __shared__ float Ws[128 * 64];  // W, natural layout

    const int tid = threadIdx.x;
    const int row0 = blockIdx.x * 64;

    for (int i = tid; i < 64 * 32; i += 256) {
        int rl = i >> 5, c4 = (i & 31) << 2;
        int r = row0 + rl;
        float4 v = make_float4(0.f, 0.f, 0.f, 0.f);
        if (r < N_NODES) v = *reinterpret_cast<const float4*>(x + (size_t)r * IN_F + c4);
        int sw = c4 ^ ((rl & 7) << 2);
        *reinterpret_cast<float4*>(&xs[rl * 128 + sw]) = v;
    }
    for (int i = tid; i < 128 * 16; i += 256) {
        int k = i >> 4, c4 = (i & 15) << 2;
        *reinterpret_cast<float4*>(&Ws[k * 64 + c4]) =
            *reinterpret_cast<const float4*>(W + k * 64 + c4);
    }
    __syncthreads();

    const int tx = tid & 15;
    const int ty = tid >> 4;
    const int c0 = tx << 2;
    const int rl0 = ty << 2;

    float acc[4][4] = {};
#pragma unroll 4
    for (int k = 0; k < 128; ++k) {
        float4 b = *reinterpret_cast<const float4*>(&Ws[k * 64 + c0]);
        float a0 = xs[(rl0 + 0) * 128 + (k ^ (((rl0 + 0) & 7) << 2))];
        float a1 = xs[(rl0 + 1) * 128 + (k ^ (((rl0 + 1) & 7) << 2))];
        float a2 = xs[(rl0 + 2) * 128 + (k ^ (((rl0 + 2) & 7) << 2))];
        float a3 = xs[(rl0 + 3) * 128 + (k ^ (((rl0 + 3) & 7) << 2))];
        acc[0][0] = fmaf(a0, b.x, acc[0][0]);
        acc[0][1] = fmaf(a0, b.y, acc[0][1]);
        acc[0][2] = fmaf(a0, b.z, acc[0][2]);
        acc[0][3] = fmaf(a0, b.w, acc[0][3]);
        acc[1][0] = fmaf(a1, b.x, acc[1][0]);
        acc[1][1] = fmaf(a1, b.y, acc[1][1]);
        acc[1][2] = fmaf(a1, b.z, acc[1][2]);
        acc[1][3] = fmaf(a1, b.w, acc[1][3]);
        acc[2][0] = fmaf(a2, b.x, acc[2][0]);
        acc[2][1] = fmaf(a2, b.y, acc[2][1]);
        acc[2][2] = fmaf(a2, b.z, acc[2][2]);
        acc[2][3] = fmaf(a2, b.w, acc[2][3]);
        acc[3][0] = fmaf(a3, b.x, acc[3][0]);
        acc[3][1] = fmaf(a3, b.y, acc[3][1]);
        acc[3][2] = fmaf(a3, b.z, acc[3][2]);
        acc[3][3] = fmaf(a3, b.w, acc[3][3]);
    }

    float at[4], ab[4];
#pragma unroll
    for (int i = 0; i < 4; i++) {
        at[i] = a[c0 + i];
        ab[i] = a[OUT_F + c0 + i];
    }

#pragma unroll
    for (int ri = 0; ri < 4; ++ri) {
        int r = row0 + rl0 + ri;
        float ps = 0.0f, pt = 0.0f;
#pragma unroll
        for (int ci = 0; ci < 4; ++ci) {
            ps = fmaf(acc[ri][ci], at[ci], ps);
            pt = fmaf(acc[ri][ci], ab[ci], pt);
        }
#pragma unroll
        for (int o = 1; o < 16; o <<= 1) {
            ps += __shfl_xor(ps, o, 64);
            pt += __shfl_xor(pt, o, 64);
        }
        if (r < N_NODES) {
            *reinterpret_cast<float4*>(Wh + (size_t)r * OUT_F + c0) =
                make_float4(acc[ri][0], acc[ri][1], acc[ri][2], acc[ri][3]);
            if (tx == 0) { sv[r] = ps; tv[r] = pt; }
        }
    }
}

// --- counting sort by src: histogram ---
__global__ void k_zero_i(int* __restrict__ p, int n) {
    int i = blockIdx.x * 256 + threadIdx.x;
    if (i < n) p[i] = 0;
}

__global__ void k_hist(const int* __restrict__ src, int* __restrict__ cnt) {
    int j = blockIdx.x * 256 + threadIdx.x;
    if (j < N_EDGES) atomicAdd(&cnt[src[j]], 1);
}

// hierarchical exclusive scan
__global__ __launch_bounds__(256) void k_scan1(const int* __restrict__ cnt,
                                               int* __restrict__ off,
                                               int* __restrict__ bsum) {
    __shared__ int s[256];
    int t = threadIdx.x;
    int i = blockIdx.x * 256 + t;
    int c = (i < N_NODES) ? cnt[i] : 0;
    s[t] = c;
    __syncthreads();
#pragma unroll
    for (int o = 1; o < 256; o <<= 1) {
        int v = (t >= o) ? s[t - o] : 0;
        __syncthreads();
        s[t] += v;
        __syncthreads();
    }
    if (i < N_NODES) off[i] = s[t] - c;
    if (t == 255) bsum[blockIdx.x] = s[255];
}

__global__ __launch_bounds__(256) void k_scan2(const int* __restrict__ bsum, int nb,
                                               int* __restrict__ boff) {
    __shared__ int s[256];
    int t = threadIdx.x;
    int c = (t < nb) ? bsum[t] : 0;
    s[t] = c;
    __syncthreads();
#pragma unroll
    for (int o = 1; o < 256; o <<= 1) {
        int v = (t >= o) ? s[t - o] : 0;
        __syncthreads();
        s[t] += v;
        __syncthreads();
    }
    if (t < nb) boff[t] = s[t] - c;
}

__global__ __launch_bounds__(256) void k_scan3(int* __restrict__ off,
                                               int* __restrict__ head,
                                               const int* __restrict__ boff) {
    int i = blockIdx.x * 256 + threadIdx.x;
    if (i < N_NODES) {
        int v = off[i] + boff[blockIdx.x];
        off[i] = v;
        head[i] = v;
    }
    if (i == 0) off[N_NODES] = N_EDGES;
}

// fused permutation + edge score + online-softmax block stats.
// One scattered 8B store per edge: rec[p] = {dst, bits(v)}.
__global__ __launch_bounds__(256) void k_permedge(const int* __restrict__ src,
                                                  const int* __restrict__ dst,
                                                  const float* __restrict__ sv,
                                                  const float* __restrict__ tv,
                                                  int* __restrict__ head,
                                                  int2* __restrict__ rec,
                                                  float* __restrict__ pmax,
                                                  float* __restrict__ psum) {
    int j = blockIdx.x * 256 + threadIdx.x;
    float v = -INFINITY;
    if (j < N_EDGES) {
        int s = src[j], d = dst[j];
        int p = atomicAdd(&head[s], 1);
        v = sv[s] + tv[d];
        v = v > 0.0f ? v : LRELU_ALPHA * v;
        rec[p] = make_int2(d, __float_as_int(v));
    }
    // per-wave online softmax stats
    float wm = wred_max(v);
    wm = __shfl(wm, 0, 64);                       // broadcast wave max
    float ev = (j < N_EDGES) ? expf(v - wm) : 0.0f;
    float wsum = wred_sum(ev);

    __shared__ float rmx[4], rsm[4];
    if ((threadIdx.x & 63) == 0) {
        rmx[threadIdx.x >> 6] = wm;
        rsm[threadIdx.x >> 6] = wsum;
    }
    __syncthreads();
    if (threadIdx.x == 0) {
        float bm = fmaxf(fmaxf(rmx[0], rmx[1]), fmaxf(rmx[2], rmx[3]));
        float bs = 0.0f;
#pragma unroll
        for (int i = 0; i < 4; i++) bs += rsm[i] * expf(rmx[i] - bm);
        pmax[blockIdx.x] = bm;
        psum[blockIdx.x] = bs;
    }
}

// combine block stats: g[0]=gmax, g[1]=1/sum
__global__ __launch_bounds__(1024) void k_rcombine(const float* __restrict__ pmax,
                                                   const float* __restrict__ psum,
                                                   int n, float* __restrict__ g) {
    __shared__ float red[16];
    __shared__ float gm_s;
    int t = threadIdx.x;
    float lmax = -INFINITY;
    for (int i = t; i < n; i += 1024) lmax = fmaxf(lmax, pmax[i]);
    float wm = wred_max(lmax);
    if ((t & 63) == 0) red[t >> 6] = wm;
    __syncthreads();
    if (t == 0) {
        float m = red[0];
        for (int i = 1; i < 16; i++) m = fmaxf(m, red[i]);
        gm_s = m;
    }
    __syncthreads();
    float gm = gm_s;
    float lsum = 0.0f;
    for (int i = t; i < n; i += 1024) lsum += psum[i] * expf(pmax[i] - gm);
    float ws = wred_sum(lsum);
    __syncthreads();
    if ((t & 63) == 0) red[t >> 6] = ws;
    __syncthreads();
    if (t == 0) {
        float s = 0.0f;
        for (int i = 0; i < 16; i++) s += red[i];
        g[0] = gm;
        g[1] = 1.0f / s;
    }
}

// K4: per-node gather; exp applied inline; out = elu(ginv * sum p*Wh[d])
__global__ __launch_bounds__(256) void k_gather(const int* __restrict__ off,
                                                const int2* __restrict__ rec,
                                                const float* __restrict__ g,
                                                const float* __restrict__ Wh,
                                                float* __restrict__ out) {
    int n = blockIdx.x * 4 + (threadIdx.x >> 6);
    int f = threadIdx.x & 63;
    if (n >= N_NODES) return;
    float gm = g[0], ginv = g[1];
    int start = off[n], end = off[n + 1];
    float acc = 0.0f;
    for (int base = start; base < end; base += 64) {
        int cnt = end - base;
        if (cnt > 64) cnt = 64;
        int dj = 0;
        float att = 0.0f;
        if (f < cnt) {
            int2 r = rec[base + f];
            dj = r.x;
            att = expf(__int_as_float(r.y) - gm);
        }
        int i = 0;
        for (; i + 3 < cnt; i += 4) {
            int j0 = __shfl(dj, i, 64), j1 = __shfl(dj, i + 1, 64);
            int j2 = __shfl(dj, i + 2, 64), j3 = __shfl(dj, i + 3, 64);
            float a0 = __shfl(att, i, 64), a1 = __shfl(att, i + 1, 64);
            float a2 = __shfl(att, i + 2, 64), a3 = __shfl(att, i + 3, 64);
            float w0 = Wh[(size_t)j0 * OUT_F + f];
            float w1 = Wh[(size_t)j1 * OUT_F + f];
            float w2 = Wh[(size_t)j2 * OUT_F + f];
            float w3 = Wh[(size_t)j3 * OUT_F + f];
            acc = fmaf(a0, w0, acc);
            acc = fmaf(a1, w1, acc);
            acc = fmaf(a2, w2, acc);
            acc = fmaf(a3, w3, acc);
        }
        for (; i < cnt; i++) {
            int jj = __shfl(dj, i, 64);
            float aa = __shfl(att, i, 64);
            acc = fmaf(aa, Wh[(size_t)jj * OUT_F + f], acc);
        }
    }
    acc *= ginv;
    out[(size_t)n * OUT_F + f] = acc > 0.0f ? acc : expm1f(acc);
}

extern "C" void kernel_launch(void* const* d_in, const int* in_sizes, int n_in,
                              void* d_out, int out_size, void* d_ws, size_t ws_size,
                              hipStream_t stream) {
    const float* x  = (const float*)d_in[0];
    const int*   ei = (const int*)d_in[1];
    const float* W  = (const float*)d_in[2];
    const float* a  = (const float*)d_in[3];
    float* out = (float*)d_out;

    const int* src = ei;            // edge_index[0]
    const int* dst = ei + N_EDGES;  // edge_index[1]

    float* ws   = (float*)d_ws;
    float* Wh   = ws;                               // 3,200,000 f
    float* sv   = Wh + (size_t)N_NODES * OUT_F;     // 50,000 f
    float* tv   = sv + N_NODES;                     // 50,000 f
    float* pmax = tv + N_NODES;                     // 4,096 f
    float* psum = pmax + 4096;                      // 4,096 f
    float* g    = psum + 4096;                      // 2 f (gmax, ginv)
    int*   cnt  = (int*)(g + 2);                    // 50,000 i
    int*   off  = cnt + N_NODES;                    // 50,001 i
    int*   head = off + N_NODES + 1;                // 50,000 i
    int*   bsum = head + N_NODES;                   // 256 i
    int*   boff = bsum + 256;                       // 256 i
    // 16B-align rec
    size_t used = (size_t)((char*)(boff + 256) - (char*)d_ws);
    used = (used + 15) & ~(size_t)15;
    int2*  rec  = (int2*)((char*)d_ws + used);      // 800,000 int2 = 6.4 MB

    const int NBN = (N_NODES + 255) / 256;   // 196
    const int NBE = (N_EDGES + 255) / 256;   // 3125

    k_zero_i<<<NBN, 256, 0, stream>>>(cnt, N_NODES);
    k_wh<<<(N_NODES + 63) / 64, 256, 0, stream>>>(x, W, a, Wh, sv, tv);
    k_hist<<<NBE, 256, 0, stream>>>(src, cnt);
    k_scan1<<<NBN, 256, 0, stream>>>(cnt, off, bsum);
    k_scan2<<<1, 256, 0, stream>>>(bsum, NBN, boff);
    k_scan3<<<NBN, 256, 0, stream>>>(off, head, boff);
    k_permedge<<<NBE, 256, 0, stream>>>(src, dst, sv, tv, head, rec, pmax, psum);
    k_rcombine<<<1, 1024, 0, stream>>>(pmax, psum, NBE, g);
    k_gather<<<(N_NODES + 3) / 4, 256, 0, stream>>>(off, rec, g, Wh, out);
}